// Round 1
// baseline (560.628 us; speedup 1.0000x reference)
//
#include <hip/hip_runtime.h>
#include <math.h>

#define N_NODES 50000
#define E_RAW 800000
#define E_TOT 850000
#define NEG_SLOPE 0.2f

__device__ __forceinline__ float lrelu(float a) { return a > 0.f ? a : NEG_SLOPE * a; }

// ---------------- CSR build (dst-major) ----------------
__global__ void k_deg(const int* __restrict__ ei, int* __restrict__ deg) {
    int e = blockIdx.x * blockDim.x + threadIdx.x;
    if (e >= E_TOT) return;
    int col = (e < E_RAW) ? ei[E_RAW + e] : (e - E_RAW);
    atomicAdd(&deg[col], 1);
}

__global__ void k_scan(const int* __restrict__ deg, int* __restrict__ off, int* __restrict__ cur) {
    __shared__ int sh[1024];
    int carry = 0;
    for (int base = 0; base < N_NODES; base += 1024) {
        int i = base + threadIdx.x;
        int v = (i < N_NODES) ? deg[i] : 0;
        sh[threadIdx.x] = v;
        __syncthreads();
        for (int ofs = 1; ofs < 1024; ofs <<= 1) {
            int t = (threadIdx.x >= ofs) ? sh[threadIdx.x - ofs] : 0;
            __syncthreads();
            sh[threadIdx.x] += t;
            __syncthreads();
        }
        if (i < N_NODES) {
            int excl = carry + sh[threadIdx.x] - v;
            off[i] = excl;
            cur[i] = excl;
        }
        carry += sh[1023];
        __syncthreads();
    }
    if (threadIdx.x == 0) off[N_NODES] = carry;
}

__global__ void k_scatter(const int* __restrict__ ei, int* __restrict__ cur, int* __restrict__ srcs) {
    int e = blockIdx.x * blockDim.x + threadIdx.x;
    if (e >= E_TOT) return;
    int row, col;
    if (e < E_RAW) { row = ei[e]; col = ei[E_RAW + e]; }
    else { row = e - E_RAW; col = row; }
    int pos = atomicAdd(&cur[col], 1);
    srcs[pos] = row;
}

// ---------------- GEMM: C[M x NC] = A[M x K] @ B[K x NC] (+bias) ----------------
// block = NC threads, 16 rows of A per block staged in LDS; M must be %16
template<int K, int NC, bool BIAS>
__global__ void k_gemm(const float* __restrict__ A, const float* __restrict__ B,
                       const float* __restrict__ bias, float* __restrict__ C, int M) {
    constexpr int MT = 16;
    __shared__ float As[MT * K];
    int m0 = blockIdx.x * MT;
    int j = threadIdx.x;
    for (int t = j; t < MT * K; t += NC) {
        As[t] = A[(size_t)(m0 + t / K) * K + (t % K)];
    }
    __syncthreads();
    float acc[MT];
#pragma unroll
    for (int m = 0; m < MT; ++m) acc[m] = 0.f;
    for (int k = 0; k < K; ++k) {
        float w = B[k * NC + j];
#pragma unroll
        for (int m = 0; m < MT; ++m) acc[m] += As[m * K + k] * w;
    }
    float bv = BIAS ? bias[j] : 0.f;
#pragma unroll
    for (int m = 0; m < MT; ++m) C[(size_t)(m0 + m) * NC + j] = acc[m] + bv;
}

// ---------------- attention dot products ----------------
// layer 1: 4 heads x 32 feats. 128 threads per node (2 nodes / 256-block)
__global__ void k_edot1(const float* __restrict__ h1, const float* __restrict__ attn,
                        float* __restrict__ es, float* __restrict__ ed) {
    int n = blockIdx.x * (blockDim.x >> 7) + (threadIdx.x >> 7);
    int t = threadIdx.x & 127;
    if (n >= N_NODES) return;
    int h = t >> 5, f = t & 31;
    float v = h1[(size_t)n * 128 + t];
    float pl = v * attn[h * 64 + f];
    float pr = v * attn[h * 64 + 32 + f];
#pragma unroll
    for (int mask = 16; mask; mask >>= 1) { pl += __shfl_xor(pl, mask); pr += __shfl_xor(pr, mask); }
    if (f == 0) { es[n * 4 + h] = pl; ed[n * 4 + h] = pr; }
}

// layer 2: 1 head x 64 feats. 64 threads (one wave) per node
__global__ void k_edot2(const float* __restrict__ h2, const float* __restrict__ attn,
                        float* __restrict__ es, float* __restrict__ ed) {
    int n = blockIdx.x * (blockDim.x >> 6) + (threadIdx.x >> 6);
    int l = threadIdx.x & 63;
    if (n >= N_NODES) return;
    float v = h2[(size_t)n * 64 + l];
    float pl = v * attn[l];
    float pr = v * attn[64 + l];
#pragma unroll
    for (int mask = 32; mask; mask >>= 1) { pl += __shfl_xor(pl, mask); pr += __shfl_xor(pr, mask); }
    if (l == 0) { es[n] = pl; ed[n] = pr; }
}

// ---------------- layer-1 segment softmax + aggregate (one wave per node) ----------------
__global__ void k_agg1(const float* __restrict__ h1, const float* __restrict__ es,
                       const float* __restrict__ ed, const int* __restrict__ off,
                       const int* __restrict__ srcs, float* __restrict__ out1) {
    int n = blockIdx.x * (blockDim.x >> 6) + (threadIdx.x >> 6);
    int lane = threadIdx.x & 63;
    if (n >= N_NODES) return;
    float edv[4];
#pragma unroll
    for (int h = 0; h < 4; ++h) edv[h] = ed[n * 4 + h];
    int s = off[n], e = off[n + 1];
    float m[4] = {-INFINITY, -INFINITY, -INFINITY, -INFINITY};
    for (int i = s + lane; i < e; i += 64) {
        int src = srcs[i];
#pragma unroll
        for (int h = 0; h < 4; ++h) {
            float a = lrelu(es[src * 4 + h] + edv[h]);
            m[h] = fmaxf(m[h], a);
        }
    }
#pragma unroll
    for (int mask = 32; mask; mask >>= 1) {
#pragma unroll
        for (int h = 0; h < 4; ++h) m[h] = fmaxf(m[h], __shfl_xor(m[h], mask));
    }
    float ssum[4] = {0.f, 0.f, 0.f, 0.f};
    for (int i = s + lane; i < e; i += 64) {
        int src = srcs[i];
#pragma unroll
        for (int h = 0; h < 4; ++h) {
            float a = lrelu(es[src * 4 + h] + edv[h]);
            ssum[h] += __expf(a - m[h]);
        }
    }
#pragma unroll
    for (int mask = 32; mask; mask >>= 1) {
#pragma unroll
        for (int h = 0; h < 4; ++h) ssum[h] += __shfl_xor(ssum[h], mask);
    }
    // lane l covers global feature l (head l>>5) and feature 64+l (head 2+(l>>5))
    int ha = lane >> 5, hb = 2 + (lane >> 5);
    float ia = 1.f / ssum[ha], ib = 1.f / ssum[hb];
    float ma = m[ha], mb = m[hb];
    float ea = edv[ha], eb = edv[hb];
    float acc_a = 0.f, acc_b = 0.f;
    for (int i = s; i < e; ++i) {
        int src = srcs[i];
        float wa = __expf(lrelu(es[src * 4 + ha] + ea) - ma) * ia;
        float wb = __expf(lrelu(es[src * 4 + hb] + eb) - mb) * ib;
        acc_a += h1[(size_t)src * 128 + lane] * wa;
        acc_b += h1[(size_t)src * 128 + 64 + lane] * wb;
    }
    // ReLU between layers fused here
    out1[(size_t)n * 128 + lane] = fmaxf(acc_a, 0.f);
    out1[(size_t)n * 128 + 64 + lane] = fmaxf(acc_b, 0.f);
}

// ---------------- layer-2 segment softmax + aggregate ----------------
__global__ void k_agg2(const float* __restrict__ h2, const float* __restrict__ es,
                       const float* __restrict__ ed, const int* __restrict__ off,
                       const int* __restrict__ srcs, float* __restrict__ outv) {
    int n = blockIdx.x * (blockDim.x >> 6) + (threadIdx.x >> 6);
    int lane = threadIdx.x & 63;
    if (n >= N_NODES) return;
    float edv = ed[n];
    int s = off[n], e = off[n + 1];
    float m = -INFINITY;
    for (int i = s + lane; i < e; i += 64) {
        float a = lrelu(es[srcs[i]] + edv);
        m = fmaxf(m, a);
    }
#pragma unroll
    for (int mask = 32; mask; mask >>= 1) m = fmaxf(m, __shfl_xor(m, mask));
    float ssum = 0.f;
    for (int i = s + lane; i < e; i += 64) {
        float a = lrelu(es[srcs[i]] + edv);
        ssum += __expf(a - m);
    }
#pragma unroll
    for (int mask = 32; mask; mask >>= 1) ssum += __shfl_xor(ssum, mask);
    float inv = 1.f / ssum;
    float acc = 0.f;
    for (int i = s; i < e; ++i) {
        int src = srcs[i];
        float w = __expf(lrelu(es[src] + edv) - m) * inv;
        acc += h2[(size_t)src * 64 + lane] * w;
    }
    outv[(size_t)n * 64 + lane] = acc;
}

extern "C" void kernel_launch(void* const* d_in, const int* in_sizes, int n_in,
                              void* d_out, int out_size, void* d_ws, size_t ws_size,
                              hipStream_t stream) {
    const float* x     = (const float*)d_in[0];
    const int*   ei    = (const int*)d_in[1];   // [2][E_RAW]
    const float* W1    = (const float*)d_in[2]; // 128x128
    const float* attn1 = (const float*)d_in[3]; // 4x64
    const float* W2    = (const float*)d_in[4]; // 128x64
    const float* attn2 = (const float*)d_in[5]; // 1x128
    const float* headW = (const float*)d_in[6]; // 64x64
    const float* headb = (const float*)d_in[7]; // 64
    float* out = (float*)d_out;

    char* ws = (char*)d_ws;
    size_t o = 0;
    auto alloc = [&](size_t bytes) -> void* {
        o = (o + 255) & ~(size_t)255;
        void* p = ws + o;
        o += bytes;
        return p;
    };
    float* h1    = (float*)alloc((size_t)N_NODES * 128 * 4);
    float* out1  = (float*)alloc((size_t)N_NODES * 128 * 4);
    float* h2    = (float*)alloc((size_t)N_NODES * 64 * 4);
    float* h2agg = (float*)alloc((size_t)N_NODES * 64 * 4);
    float* e1s   = (float*)alloc((size_t)N_NODES * 4 * 4);
    float* e1d   = (float*)alloc((size_t)N_NODES * 4 * 4);
    float* e2s   = (float*)alloc((size_t)N_NODES * 4);
    float* e2d   = (float*)alloc((size_t)N_NODES * 4);
    int*   deg   = (int*)alloc((size_t)N_NODES * 4);
    int*   off   = (int*)alloc((size_t)(N_NODES + 1) * 4);
    int*   cur   = (int*)alloc((size_t)N_NODES * 4);
    int*   srcs  = (int*)alloc((size_t)E_TOT * 4);

    // CSR build
    hipMemsetAsync(deg, 0, (size_t)N_NODES * 4, stream);
    k_deg<<<(E_TOT + 255) / 256, 256, 0, stream>>>(ei, deg);
    k_scan<<<1, 1024, 0, stream>>>(deg, off, cur);
    k_scatter<<<(E_TOT + 255) / 256, 256, 0, stream>>>(ei, cur, srcs);

    // layer 1
    k_gemm<128, 128, false><<<N_NODES / 16, 128, 0, stream>>>(x, W1, nullptr, h1, N_NODES);
    k_edot1<<<N_NODES / 2, 256, 0, stream>>>(h1, attn1, e1s, e1d);
    k_agg1<<<N_NODES / 4, 256, 0, stream>>>(h1, e1s, e1d, off, srcs, out1);

    // layer 2
    k_gemm<128, 64, false><<<N_NODES / 16, 64, 0, stream>>>(out1, W2, nullptr, h2, N_NODES);
    k_edot2<<<N_NODES / 4, 256, 0, stream>>>(h2, attn2, e2s, e2d);
    k_agg2<<<N_NODES / 4, 256, 0, stream>>>(h2, e2s, e2d, off, srcs, h2agg);

    // head
    k_gemm<64, 64, true><<<N_NODES / 16, 64, 0, stream>>>(h2agg, headW, headb, out, N_NODES);
}

// Round 2
// 411.122 us; speedup vs baseline: 1.3637x; 1.3637x over previous
//
#include <hip/hip_runtime.h>
#include <math.h>

#define N_NODES 50000
#define E_RAW 800000
#define E_TOT 850000
#define NEG_SLOPE 0.2f
#define NBLK ((N_NODES + 1023) / 1024)

__device__ __forceinline__ float lrelu(float a) { return a > 0.f ? a : NEG_SLOPE * a; }

// ---------------- CSR build (dst-major) ----------------
__global__ void k_deg(const int* __restrict__ ei, int* __restrict__ deg) {
    int e = blockIdx.x * blockDim.x + threadIdx.x;
    if (e >= E_TOT) return;
    int col = (e < E_RAW) ? ei[E_RAW + e] : (e - E_RAW);
    atomicAdd(&deg[col], 1);
}

// block-local exclusive scan (49 parallel blocks)
__global__ void k_scan1(const int* __restrict__ deg, int* __restrict__ off, int* __restrict__ blksum) {
    __shared__ int sh[1024];
    int b = blockIdx.x;
    int i = b * 1024 + threadIdx.x;
    int v = (i < N_NODES) ? deg[i] : 0;
    sh[threadIdx.x] = v;
    __syncthreads();
    for (int ofs = 1; ofs < 1024; ofs <<= 1) {
        int t = (threadIdx.x >= ofs) ? sh[threadIdx.x - ofs] : 0;
        __syncthreads();
        sh[threadIdx.x] += t;
        __syncthreads();
    }
    if (i < N_NODES) off[i] = sh[threadIdx.x] - v;
    if (threadIdx.x == 1023) blksum[b] = sh[1023];
}

// one-wave scan of the 49 block sums
__global__ void k_scan2(const int* __restrict__ blksum, int* __restrict__ blkoff, int* __restrict__ off) {
    int l = threadIdx.x & 63;
    int v = (l < NBLK) ? blksum[l] : 0;
    int incl = v;
    for (int ofs = 1; ofs < 64; ofs <<= 1) {
        int t = __shfl_up(incl, ofs);
        if (l >= ofs) incl += t;
    }
    if (l < NBLK) blkoff[l] = incl - v;
    if (l == 63) off[N_NODES] = incl;   // grand total
}

__global__ void k_scan3(int* __restrict__ off, const int* __restrict__ blkoff, int* __restrict__ cur) {
    int i = blockIdx.x * blockDim.x + threadIdx.x;
    if (i >= N_NODES) return;
    int v = off[i] + blkoff[i >> 10];
    off[i] = v;
    cur[i] = v;
}

__global__ void k_scatter(const int* __restrict__ ei, int* __restrict__ cur, int* __restrict__ srcs) {
    int e = blockIdx.x * blockDim.x + threadIdx.x;
    if (e >= E_TOT) return;
    int row, col;
    if (e < E_RAW) { row = ei[e]; col = ei[E_RAW + e]; }
    else { row = e - E_RAW; col = row; }
    int pos = atomicAdd(&cur[col], 1);
    srcs[pos] = row;
}

// ---------------- GEMM: C[M x NC] = A[M x K] @ B[K x NC] (+bias) ----------------
template<int K, int NC, bool BIAS>
__global__ void k_gemm(const float* __restrict__ A, const float* __restrict__ B,
                       const float* __restrict__ bias, float* __restrict__ C, int M) {
    constexpr int MT = 16;
    __shared__ float As[MT * K];
    int m0 = blockIdx.x * MT;
    int j = threadIdx.x;
    const float4* Ab = (const float4*)(A + (size_t)m0 * K);
    float4* As4 = (float4*)As;
    for (int t = j; t < MT * K / 4; t += NC) As4[t] = Ab[t];
    __syncthreads();
    float acc[MT];
#pragma unroll
    for (int m = 0; m < MT; ++m) acc[m] = 0.f;
    for (int k = 0; k < K; ++k) {
        float w = B[k * NC + j];
#pragma unroll
        for (int m = 0; m < MT; ++m) acc[m] += As[m * K + k] * w;
    }
    float bv = BIAS ? bias[j] : 0.f;
#pragma unroll
    for (int m = 0; m < MT; ++m) C[(size_t)(m0 + m) * NC + j] = acc[m] + bv;
}

// ---------------- attention dot products ----------------
__global__ void k_edot1(const float* __restrict__ h1, const float* __restrict__ attn,
                        float* __restrict__ es, float* __restrict__ ed) {
    int n = blockIdx.x * (blockDim.x >> 7) + (threadIdx.x >> 7);
    int t = threadIdx.x & 127;
    if (n >= N_NODES) return;
    int h = t >> 5, f = t & 31;
    float v = h1[(size_t)n * 128 + t];
    float pl = v * attn[h * 64 + f];
    float pr = v * attn[h * 64 + 32 + f];
#pragma unroll
    for (int mask = 16; mask; mask >>= 1) { pl += __shfl_xor(pl, mask); pr += __shfl_xor(pr, mask); }
    if (f == 0) { es[n * 4 + h] = pl; ed[n * 4 + h] = pr; }
}

__global__ void k_edot2(const float* __restrict__ h2, const float* __restrict__ attn,
                        float* __restrict__ es, float* __restrict__ ed) {
    int n = blockIdx.x * (blockDim.x >> 6) + (threadIdx.x >> 6);
    int l = threadIdx.x & 63;
    if (n >= N_NODES) return;
    float v = h2[(size_t)n * 64 + l];
    float pl = v * attn[l];
    float pr = v * attn[64 + l];
#pragma unroll
    for (int mask = 32; mask; mask >>= 1) { pl += __shfl_xor(pl, mask); pr += __shfl_xor(pr, mask); }
    if (l == 0) { es[n] = pl; ed[n] = pr; }
}

// ---------------- layer-1 segment softmax + aggregate ----------------
// one wave per node. Weight for (edge j, head h) computed ONCE by lane j*4+h,
// broadcast via shuffles; denominator fused into the aggregation pass.
__global__ void k_agg1(const float* __restrict__ h1, const float* __restrict__ es,
                       const float* __restrict__ ed, const int* __restrict__ off,
                       const int* __restrict__ srcs, float* __restrict__ out1) {
    int n = blockIdx.x * (blockDim.x >> 6) + (threadIdx.x >> 6);
    int lane = threadIdx.x & 63;
    if (n >= N_NODES) return;
    float4 e4 = *(const float4*)(ed + n * 4);
    float edv[4] = {e4.x, e4.y, e4.z, e4.w};
    int s = off[n], e = off[n + 1];
    // phase 1: per-head max (lanes stride edges)
    float m[4] = {-INFINITY, -INFINITY, -INFINITY, -INFINITY};
    for (int i = s + lane; i < e; i += 64) {
        int src = srcs[i];
        float4 ev = *(const float4*)(es + src * 4);
        m[0] = fmaxf(m[0], lrelu(ev.x + edv[0]));
        m[1] = fmaxf(m[1], lrelu(ev.y + edv[1]));
        m[2] = fmaxf(m[2], lrelu(ev.z + edv[2]));
        m[3] = fmaxf(m[3], lrelu(ev.w + edv[3]));
    }
#pragma unroll
    for (int mask = 32; mask; mask >>= 1) {
#pragma unroll
        for (int h = 0; h < 4; ++h) m[h] = fmaxf(m[h], __shfl_xor(m[h], mask));
    }
    // phase 2: fused weight + denominator + aggregation, 16 edges/chunk
    int ha = lane >> 5, hb = ha + 2;
    int myh = lane & 3;
    float mh = m[myh], edh = edv[myh];
    const float* pa = h1 + lane;
    const float* pb = h1 + 64 + lane;
    float acc_a = 0.f, acc_b = 0.f, psum = 0.f;
    int base = s;
    for (; base + 16 <= e; base += 16) {
        int j = lane >> 2;
        int srcj = srcs[base + j];
        float w = __expf(lrelu(es[srcj * 4 + myh] + edh) - mh);
        psum += w;
#pragma unroll
        for (int j2 = 0; j2 < 16; ++j2) {
            int src = __shfl(srcj, j2 * 4);
            float wa = __shfl(w, j2 * 4 + ha);
            float wb = __shfl(w, j2 * 4 + hb);
            acc_a += pa[(size_t)src * 128] * wa;
            acc_b += pb[(size_t)src * 128] * wb;
        }
    }
    if (base < e) {
        int cnt = e - base;
        int j = lane >> 2;
        float w = 0.f;
        int srcj = 0;
        if (j < cnt) {
            srcj = srcs[base + j];
            w = __expf(lrelu(es[srcj * 4 + myh] + edh) - mh);
        }
        psum += w;
        for (int j2 = 0; j2 < cnt; ++j2) {
            int src = __shfl(srcj, j2 * 4);
            float wa = __shfl(w, j2 * 4 + ha);
            float wb = __shfl(w, j2 * 4 + hb);
            acc_a += pa[(size_t)src * 128] * wa;
            acc_b += pb[(size_t)src * 128] * wb;
        }
    }
    // reduce psum per head-class (lanes with equal lane&3)
#pragma unroll
    for (int mask = 4; mask <= 32; mask <<= 1) psum += __shfl_xor(psum, mask);
    float sa = __shfl(psum, ha);   // lane h (0..3) holds head-h total
    float sb = __shfl(psum, hb);
    // ReLU between layers fused here
    out1[(size_t)n * 128 + lane] = fmaxf(acc_a / sa, 0.f);
    out1[(size_t)n * 128 + 64 + lane] = fmaxf(acc_b / sb, 0.f);
}

// ---------------- layer-2 segment softmax + aggregate ----------------
__global__ void k_agg2(const float* __restrict__ h2, const float* __restrict__ es,
                       const float* __restrict__ ed, const int* __restrict__ off,
                       const int* __restrict__ srcs, float* __restrict__ outv) {
    int n = blockIdx.x * (blockDim.x >> 6) + (threadIdx.x >> 6);
    int lane = threadIdx.x & 63;
    if (n >= N_NODES) return;
    float edv = ed[n];
    int s = off[n], e = off[n + 1];
    float m = -INFINITY;
    for (int i = s + lane; i < e; i += 64)
        m = fmaxf(m, lrelu(es[srcs[i]] + edv));
#pragma unroll
    for (int mask = 32; mask; mask >>= 1) m = fmaxf(m, __shfl_xor(m, mask));
    float acc = 0.f, psum = 0.f;
    for (int base = s; base < e; base += 64) {
        int cnt = min(64, e - base);
        float w = 0.f;
        int srcj = 0;
        if (lane < cnt) {
            srcj = srcs[base + lane];
            w = __expf(lrelu(es[srcj] + edv) - m);
        }
        psum += w;
        for (int j = 0; j < cnt; ++j) {
            int src = __shfl(srcj, j);
            float wj = __shfl(w, j);
            acc += h2[(size_t)src * 64 + lane] * wj;
        }
    }
#pragma unroll
    for (int mask = 32; mask; mask >>= 1) psum += __shfl_xor(psum, mask);
    outv[(size_t)n * 64 + lane] = acc * (1.f / psum);
}

extern "C" void kernel_launch(void* const* d_in, const int* in_sizes, int n_in,
                              void* d_out, int out_size, void* d_ws, size_t ws_size,
                              hipStream_t stream) {
    const float* x     = (const float*)d_in[0];
    const int*   ei    = (const int*)d_in[1];   // [2][E_RAW]
    const float* W1    = (const float*)d_in[2]; // 128x128
    const float* attn1 = (const float*)d_in[3]; // 4x64
    const float* W2    = (const float*)d_in[4]; // 128x64
    const float* attn2 = (const float*)d_in[5]; // 1x128
    const float* headW = (const float*)d_in[6]; // 64x64
    const float* headb = (const float*)d_in[7]; // 64
    float* out = (float*)d_out;

    char* ws = (char*)d_ws;
    size_t o = 0;
    auto alloc = [&](size_t bytes) -> void* {
        o = (o + 255) & ~(size_t)255;
        void* p = ws + o;
        o += bytes;
        return p;
    };
    float* h1     = (float*)alloc((size_t)N_NODES * 128 * 4);
    float* out1   = (float*)alloc((size_t)N_NODES * 128 * 4);
    float* h2     = (float*)alloc((size_t)N_NODES * 64 * 4);
    float* h2agg  = (float*)alloc((size_t)N_NODES * 64 * 4);
    float* e1s    = (float*)alloc((size_t)N_NODES * 4 * 4);
    float* e1d    = (float*)alloc((size_t)N_NODES * 4 * 4);
    float* e2s    = (float*)alloc((size_t)N_NODES * 4);
    float* e2d    = (float*)alloc((size_t)N_NODES * 4);
    int*   deg    = (int*)alloc((size_t)N_NODES * 4);
    int*   off    = (int*)alloc((size_t)(N_NODES + 1) * 4);
    int*   cur    = (int*)alloc((size_t)N_NODES * 4);
    int*   srcs   = (int*)alloc((size_t)E_TOT * 4);
    int*   blksum = (int*)alloc((size_t)NBLK * 4);
    int*   blkoff = (int*)alloc((size_t)NBLK * 4);

    // CSR build
    hipMemsetAsync(deg, 0, (size_t)N_NODES * 4, stream);
    k_deg<<<(E_TOT + 255) / 256, 256, 0, stream>>>(ei, deg);
    k_scan1<<<NBLK, 1024, 0, stream>>>(deg, off, blksum);
    k_scan2<<<1, 64, 0, stream>>>(blksum, blkoff, off);
    k_scan3<<<(N_NODES + 255) / 256, 256, 0, stream>>>(off, blkoff, cur);
    k_scatter<<<(E_TOT + 255) / 256, 256, 0, stream>>>(ei, cur, srcs);

    // layer 1
    k_gemm<128, 128, false><<<N_NODES / 16, 128, 0, stream>>>(x, W1, nullptr, h1, N_NODES);
    k_edot1<<<N_NODES / 2, 256, 0, stream>>>(h1, attn1, e1s, e1d);
    k_agg1<<<N_NODES / 4, 256, 0, stream>>>(h1, e1s, e1d, off, srcs, out1);

    // layer 2
    k_gemm<128, 64, false><<<N_NODES / 16, 64, 0, stream>>>(out1, W2, nullptr, h2, N_NODES);
    k_edot2<<<N_NODES / 4, 256, 0, stream>>>(h2, attn2, e2s, e2d);
    k_agg2<<<N_NODES / 4, 256, 0, stream>>>(h2, e2s, e2d, off, srcs, h2agg);

    // head
    k_gemm<64, 64, true><<<N_NODES / 16, 64, 0, stream>>>(h2agg, headW, headb, out, N_NODES);
}

// Round 3
// 387.774 us; speedup vs baseline: 1.4458x; 1.0602x over previous
//
#include <hip/hip_runtime.h>
#include <math.h>

#define N_NODES 50000
#define E_RAW 800000
#define E_TOT 850000
#define NEG_SLOPE 0.2f
#define NBLK ((N_NODES + 1023) / 1024)

__device__ __forceinline__ float lrelu(float a) { return a > 0.f ? a : NEG_SLOPE * a; }

// ---------------- CSR build (dst-major) ----------------
__global__ void k_deg(const int* __restrict__ ei, int* __restrict__ deg) {
    int e = blockIdx.x * blockDim.x + threadIdx.x;
    if (e >= E_TOT) return;
    int col = (e < E_RAW) ? ei[E_RAW + e] : (e - E_RAW);
    atomicAdd(&deg[col], 1);
}

__global__ void k_scan1(const int* __restrict__ deg, int* __restrict__ off, int* __restrict__ blksum) {
    __shared__ int sh[1024];
    int b = blockIdx.x;
    int i = b * 1024 + threadIdx.x;
    int v = (i < N_NODES) ? deg[i] : 0;
    sh[threadIdx.x] = v;
    __syncthreads();
    for (int ofs = 1; ofs < 1024; ofs <<= 1) {
        int t = (threadIdx.x >= ofs) ? sh[threadIdx.x - ofs] : 0;
        __syncthreads();
        sh[threadIdx.x] += t;
        __syncthreads();
    }
    if (i < N_NODES) off[i] = sh[threadIdx.x] - v;
    if (threadIdx.x == 1023) blksum[b] = sh[1023];
}

__global__ void k_scan2(const int* __restrict__ blksum, int* __restrict__ blkoff, int* __restrict__ off) {
    int l = threadIdx.x & 63;
    int v = (l < NBLK) ? blksum[l] : 0;
    int incl = v;
    for (int ofs = 1; ofs < 64; ofs <<= 1) {
        int t = __shfl_up(incl, ofs);
        if (l >= ofs) incl += t;
    }
    if (l < NBLK) blkoff[l] = incl - v;
    if (l == 63) off[N_NODES] = incl;
}

__global__ void k_scan3(int* __restrict__ off, const int* __restrict__ blkoff, int* __restrict__ cur) {
    int i = blockIdx.x * blockDim.x + threadIdx.x;
    if (i >= N_NODES) return;
    int v = off[i] + blkoff[i >> 10];
    off[i] = v;
    cur[i] = v;
}

__global__ void k_scatter(const int* __restrict__ ei, int* __restrict__ cur, int* __restrict__ srcs) {
    int e = blockIdx.x * blockDim.x + threadIdx.x;
    if (e >= E_TOT) return;
    int row, col;
    if (e < E_RAW) { row = ei[e]; col = ei[E_RAW + e]; }
    else { row = e - E_RAW; col = row; }
    int pos = atomicAdd(&cur[col], 1);
    srcs[pos] = row;
}

// ---------------- GEMM + fused attention-dot epilogue ----------------
// C[M x NC] = A[M x K] @ B[K x NC]. EPI: 0=none, 1=attn1 (4 heads x 32), 2=attn2 (1 head x 64), 3=+bias
template<int K, int NC, int EPI>
__global__ void k_gemm(const float* __restrict__ A, const float* __restrict__ B,
                       const float* __restrict__ aux, float* __restrict__ C,
                       float* __restrict__ es, float* __restrict__ ed) {
    constexpr int MT = 16;
    __shared__ float As[MT * K];
    int m0 = blockIdx.x * MT;
    int j = threadIdx.x;
    const float4* Ab = (const float4*)(A + (size_t)m0 * K);
    float4* As4 = (float4*)As;
    for (int t = j; t < MT * K / 4; t += NC) As4[t] = Ab[t];
    __syncthreads();
    float acc[MT];
#pragma unroll
    for (int m = 0; m < MT; ++m) acc[m] = 0.f;
    const float4* As4r = (const float4*)As;
    for (int kk = 0; kk < K / 4; ++kk) {
        float w0 = B[(4 * kk + 0) * NC + j];
        float w1 = B[(4 * kk + 1) * NC + j];
        float w2 = B[(4 * kk + 2) * NC + j];
        float w3 = B[(4 * kk + 3) * NC + j];
#pragma unroll
        for (int m = 0; m < MT; ++m) {
            float4 a = As4r[m * (K / 4) + kk];
            acc[m] += a.x * w0 + a.y * w1 + a.z * w2 + a.w * w3;
        }
    }
    float bv = (EPI == 3) ? aux[j] : 0.f;
#pragma unroll
    for (int m = 0; m < MT; ++m) C[(size_t)(m0 + m) * NC + j] = acc[m] + bv;

    if (EPI == 1) {
        // 4 heads x 32 feats; j in [0,128): head = j>>5, feat = j&31 (head group = 32-lane subgroup)
        int f = j & 31, h = j >> 5;
        float al = aux[h * 64 + f];
        float ar = aux[h * 64 + 32 + f];
#pragma unroll
        for (int m = 0; m < MT; ++m) {
            float pl = acc[m] * al, pr = acc[m] * ar;
#pragma unroll
            for (int mask = 16; mask; mask >>= 1) { pl += __shfl_xor(pl, mask); pr += __shfl_xor(pr, mask); }
            if (f == 0) { es[(m0 + m) * 4 + h] = pl; ed[(m0 + m) * 4 + h] = pr; }
        }
    }
    if (EPI == 2) {
        // 1 head x 64 feats; block = 64 threads = 1 wave
        float al = aux[j], ar = aux[64 + j];
#pragma unroll
        for (int m = 0; m < MT; ++m) {
            float pl = acc[m] * al, pr = acc[m] * ar;
#pragma unroll
            for (int mask = 32; mask; mask >>= 1) { pl += __shfl_xor(pl, mask); pr += __shfl_xor(pr, mask); }
            if (j == 0) { es[m0 + m] = pl; ed[m0 + m] = pr; }
        }
    }
}

// ---------------- layer-1 fused softmax+aggregate: one wave per node ----------------
// lane l covers features 2l,2l+1 (head hc=l>>4). Weight for (edge j, head h) computed
// once by lane j*4+h; no max pass (exp args bounded ~|6|, fp32-safe).
__global__ void k_agg1(const float* __restrict__ h1, const float* __restrict__ es,
                       const float* __restrict__ ed, const int* __restrict__ off,
                       const int* __restrict__ srcs, float* __restrict__ out1) {
    int n = blockIdx.x * (blockDim.x >> 6) + (threadIdx.x >> 6);
    int lane = threadIdx.x & 63;
    if (n >= N_NODES) return;
    int myh = lane & 3;
    float edh = ed[n * 4 + myh];
    int hc = lane >> 4;
    int s = off[n], e = off[n + 1];
    const float2* gp = (const float2*)h1;   // row = 64 float2
    float ax = 0.f, ay = 0.f, psum = 0.f;
    for (int base = s; base < e; base += 16) {
        int cnt = min(16, e - base);
        int jj = lane >> 2;
        float w = 0.f;
        int srcj = 0;
        if (jj < cnt) {
            srcj = srcs[base + jj];
            w = __expf(lrelu(es[srcj * 4 + myh] + edh));
        }
        psum += w;
        for (int j2 = 0; j2 < cnt; ++j2) {
            int src = __shfl(srcj, j2 * 4);
            float wc = __shfl(w, j2 * 4 + hc);
            float2 v = gp[(size_t)src * 64 + lane];
            ax += v.x * wc;
            ay += v.y * wc;
        }
    }
#pragma unroll
    for (int mask = 4; mask <= 32; mask <<= 1) psum += __shfl_xor(psum, mask);
    float inv = 1.f / __shfl(psum, hc);
    float2 o;
    o.x = fmaxf(ax * inv, 0.f);   // fused inter-layer ReLU
    o.y = fmaxf(ay * inv, 0.f);
    ((float2*)out1)[(size_t)n * 64 + lane] = o;
}

// ---------------- layer-2 fused softmax+aggregate: HALF-wave per node ----------------
// 32 lanes x float2 cover the 64 feats; 2 nodes per wave.
__global__ void k_agg2(const float* __restrict__ h2, const float* __restrict__ es,
                       const float* __restrict__ ed, const int* __restrict__ off,
                       const int* __restrict__ srcs, float* __restrict__ outv) {
    int n = blockIdx.x * (blockDim.x >> 5) + (threadIdx.x >> 5);
    int l = threadIdx.x & 31;
    int hb = threadIdx.x & 32;   // base lane of my half within the wave
    if (n >= N_NODES) return;
    float edv = ed[n];
    int s = off[n], e = off[n + 1];
    const float2* gp = (const float2*)h2;   // row = 32 float2
    float ax = 0.f, ay = 0.f, psum = 0.f;
    for (int base = s; base < e; base += 32) {
        int cnt = min(32, e - base);
        float w = 0.f;
        int srcj = 0;
        if (l < cnt) {
            srcj = srcs[base + l];
            w = __expf(lrelu(es[srcj] + edv));
        }
        psum += w;
        for (int j = 0; j < cnt; ++j) {
            int src = __shfl(srcj, hb + j);
            float wj = __shfl(w, hb + j);
            float2 v = gp[(size_t)src * 32 + l];
            ax += v.x * wj;
            ay += v.y * wj;
        }
    }
#pragma unroll
    for (int mask = 1; mask <= 16; mask <<= 1) psum += __shfl_xor(psum, mask);
    float inv = 1.f / psum;
    float2 o; o.x = ax * inv; o.y = ay * inv;
    ((float2*)outv)[(size_t)n * 32 + l] = o;
}

extern "C" void kernel_launch(void* const* d_in, const int* in_sizes, int n_in,
                              void* d_out, int out_size, void* d_ws, size_t ws_size,
                              hipStream_t stream) {
    const float* x     = (const float*)d_in[0];
    const int*   ei    = (const int*)d_in[1];
    const float* W1    = (const float*)d_in[2];
    const float* attn1 = (const float*)d_in[3];
    const float* W2    = (const float*)d_in[4];
    const float* attn2 = (const float*)d_in[5];
    const float* headW = (const float*)d_in[6];
    const float* headb = (const float*)d_in[7];
    float* out = (float*)d_out;

    char* ws = (char*)d_ws;
    size_t o = 0;
    auto alloc = [&](size_t bytes) -> void* {
        o = (o + 255) & ~(size_t)255;
        void* p = ws + o;
        o += bytes;
        return p;
    };
    float* h1     = (float*)alloc((size_t)N_NODES * 128 * 4);
    float* out1   = (float*)alloc((size_t)N_NODES * 128 * 4);
    float* h2     = (float*)alloc((size_t)N_NODES * 64 * 4);
    float* h2agg  = (float*)alloc((size_t)N_NODES * 64 * 4);
    float* e1s    = (float*)alloc((size_t)N_NODES * 4 * 4);
    float* e1d    = (float*)alloc((size_t)N_NODES * 4 * 4);
    float* e2s    = (float*)alloc((size_t)N_NODES * 4);
    float* e2d    = (float*)alloc((size_t)N_NODES * 4);
    int*   deg    = (int*)alloc((size_t)N_NODES * 4);
    int*   off    = (int*)alloc((size_t)(N_NODES + 1) * 4);
    int*   cur    = (int*)alloc((size_t)N_NODES * 4);
    int*   srcs   = (int*)alloc((size_t)E_TOT * 4);
    int*   blksum = (int*)alloc((size_t)NBLK * 4);
    int*   blkoff = (int*)alloc((size_t)NBLK * 4);

    // CSR build
    hipMemsetAsync(deg, 0, (size_t)N_NODES * 4, stream);
    k_deg<<<(E_TOT + 255) / 256, 256, 0, stream>>>(ei, deg);
    k_scan1<<<NBLK, 1024, 0, stream>>>(deg, off, blksum);
    k_scan2<<<1, 64, 0, stream>>>(blksum, blkoff, off);
    k_scan3<<<(N_NODES + 255) / 256, 256, 0, stream>>>(off, blkoff, cur);
    k_scatter<<<(E_TOT + 255) / 256, 256, 0, stream>>>(ei, cur, srcs);

    // layer 1 (edot fused into GEMM epilogue)
    k_gemm<128, 128, 1><<<N_NODES / 16, 128, 0, stream>>>(x, W1, attn1, h1, e1s, e1d);
    k_agg1<<<N_NODES / 4, 256, 0, stream>>>(h1, e1s, e1d, off, srcs, out1);

    // layer 2
    k_gemm<128, 64, 2><<<N_NODES / 16, 64, 0, stream>>>(out1, W2, attn2, h2, e2s, e2d);
    k_agg2<<<N_NODES / 8, 256, 0, stream>>>(h2, e2s, e2d, off, srcs, h2agg);

    // head
    k_gemm<64, 64, 3><<<N_NODES / 16, 64, 0, stream>>>(h2agg, headW, headb, out, nullptr, nullptr);
}

// Round 4
// 340.397 us; speedup vs baseline: 1.6470x; 1.1392x over previous
//
#include <hip/hip_runtime.h>
#include <math.h>

#define N_NODES 50000
#define E_RAW 800000
#define E_TOT 850000
#define NEG_SLOPE 0.2f
#define NBLK ((N_NODES + 1023) / 1024)

__device__ __forceinline__ float lrelu(float a) { return a > 0.f ? a : NEG_SLOPE * a; }

// bf16 pack/unpack (RNE), manual to keep logits fp32 and payload bf16
__device__ __forceinline__ unsigned short f2bf(float f) {
    unsigned u = __float_as_uint(f);
    return (unsigned short)((u + 0x7fff + ((u >> 16) & 1)) >> 16);
}
__device__ __forceinline__ float bflo(unsigned p) { return __uint_as_float(p << 16); }
__device__ __forceinline__ float bfhi(unsigned p) { return __uint_as_float(p & 0xffff0000u); }

// ---------------- CSR build (dst-major) ----------------
__global__ void k_deg(const int* __restrict__ ei, int* __restrict__ deg) {
    int e = blockIdx.x * blockDim.x + threadIdx.x;
    if (e >= E_TOT) return;
    int col = (e < E_RAW) ? ei[E_RAW + e] : (e - E_RAW);
    atomicAdd(&deg[col], 1);
}

__global__ void k_scan1(const int* __restrict__ deg, int* __restrict__ off, int* __restrict__ blksum) {
    __shared__ int sh[1024];
    int b = blockIdx.x;
    int i = b * 1024 + threadIdx.x;
    int v = (i < N_NODES) ? deg[i] : 0;
    sh[threadIdx.x] = v;
    __syncthreads();
    for (int ofs = 1; ofs < 1024; ofs <<= 1) {
        int t = (threadIdx.x >= ofs) ? sh[threadIdx.x - ofs] : 0;
        __syncthreads();
        sh[threadIdx.x] += t;
        __syncthreads();
    }
    if (i < N_NODES) off[i] = sh[threadIdx.x] - v;
    if (threadIdx.x == 1023) blksum[b] = sh[1023];
}

__global__ void k_scan2(const int* __restrict__ blksum, int* __restrict__ blkoff, int* __restrict__ off) {
    int l = threadIdx.x & 63;
    int v = (l < NBLK) ? blksum[l] : 0;
    int incl = v;
    for (int ofs = 1; ofs < 64; ofs <<= 1) {
        int t = __shfl_up(incl, ofs);
        if (l >= ofs) incl += t;
    }
    if (l < NBLK) blkoff[l] = incl - v;
    if (l == 63) off[N_NODES] = incl;
}

__global__ void k_scan3(int* __restrict__ off, const int* __restrict__ blkoff, int* __restrict__ cur) {
    int i = blockIdx.x * blockDim.x + threadIdx.x;
    if (i >= N_NODES) return;
    int v = off[i] + blkoff[i >> 10];
    off[i] = v;
    cur[i] = v;
}

__global__ void k_scatter(const int* __restrict__ ei, int* __restrict__ cur, int* __restrict__ srcs) {
    int e = blockIdx.x * blockDim.x + threadIdx.x;
    if (e >= E_TOT) return;
    int row, col;
    if (e < E_RAW) { row = ei[e]; col = ei[E_RAW + e]; }
    else { row = e - E_RAW; col = row; }
    int pos = atomicAdd(&cur[col], 1);
    srcs[pos] = row;
}

// ---------------- GEMM + fused attention-dot epilogue ----------------
// EPI: 1 = attn1 (4hx32) + bf16 C out; 2 = attn2 (1hx64) + bf16 C out; 3 = +bias, fp32 C out
template<int K, int NC, int EPI>
__global__ void k_gemm(const float* __restrict__ A, const float* __restrict__ B,
                       const float* __restrict__ aux, void* __restrict__ Cv,
                       float* __restrict__ es, float* __restrict__ ed) {
    constexpr int MT = 16;
    __shared__ float As[MT * K];
    int m0 = blockIdx.x * MT;
    int j = threadIdx.x;
    const float4* Ab = (const float4*)(A + (size_t)m0 * K);
    float4* As4 = (float4*)As;
    for (int t = j; t < MT * K / 4; t += NC) As4[t] = Ab[t];
    __syncthreads();
    float acc[MT];
#pragma unroll
    for (int m = 0; m < MT; ++m) acc[m] = 0.f;
    const float4* As4r = (const float4*)As;
    for (int kk = 0; kk < K / 4; ++kk) {
        float w0 = B[(4 * kk + 0) * NC + j];
        float w1 = B[(4 * kk + 1) * NC + j];
        float w2 = B[(4 * kk + 2) * NC + j];
        float w3 = B[(4 * kk + 3) * NC + j];
#pragma unroll
        for (int m = 0; m < MT; ++m) {
            float4 a = As4r[m * (K / 4) + kk];
            acc[m] += a.x * w0 + a.y * w1 + a.z * w2 + a.w * w3;
        }
    }
    if (EPI == 3) {
        float bv = aux[j];
        float* C = (float*)Cv;
#pragma unroll
        for (int m = 0; m < MT; ++m) C[(size_t)(m0 + m) * NC + j] = acc[m] + bv;
    } else {
        unsigned short* C = (unsigned short*)Cv;
#pragma unroll
        for (int m = 0; m < MT; ++m) C[(size_t)(m0 + m) * NC + j] = f2bf(acc[m]);
    }

    if (EPI == 1) {
        int f = j & 31, h = j >> 5;
        float al = aux[h * 64 + f];
        float ar = aux[h * 64 + 32 + f];
#pragma unroll
        for (int m = 0; m < MT; ++m) {
            float pl = acc[m] * al, pr = acc[m] * ar;
#pragma unroll
            for (int mask = 16; mask; mask >>= 1) { pl += __shfl_xor(pl, mask); pr += __shfl_xor(pr, mask); }
            if (f == 0) { es[(m0 + m) * 4 + h] = pl; ed[(m0 + m) * 4 + h] = pr; }
        }
    }
    if (EPI == 2) {
        float al = aux[j], ar = aux[64 + j];
#pragma unroll
        for (int m = 0; m < MT; ++m) {
            float pl = acc[m] * al, pr = acc[m] * ar;
#pragma unroll
            for (int mask = 32; mask; mask >>= 1) { pl += __shfl_xor(pl, mask); pr += __shfl_xor(pr, mask); }
            if (j == 0) { es[m0 + m] = pl; ed[m0 + m] = pr; }
        }
    }
}

// ---------------- layer-1 fused softmax+aggregate: one wave per node ----------------
// bf16 payload (lane l = feats 2l,2l+1, head hc=l>>4). 16-edge chunks, fully unrolled;
// invalid slots get src=0/w=0 (row-0 dummy load is L1-hot, weight 0 keeps it exact).
__global__ void k_agg1(const unsigned* __restrict__ h1b, const float* __restrict__ es,
                       const float* __restrict__ ed, const int* __restrict__ off,
                       const int* __restrict__ srcs, float* __restrict__ out1) {
    int n = blockIdx.x * (blockDim.x >> 6) + (threadIdx.x >> 6);
    int lane = threadIdx.x & 63;
    if (n >= N_NODES) return;
    int myh = lane & 3;
    float edh = ed[n * 4 + myh];
    int hc = lane >> 4;
    int s = off[n], e = off[n + 1];
    int jj = lane >> 2;
    float ax = 0.f, ay = 0.f, psum = 0.f;
    for (int base = s; base < e; base += 16) {
        int cnt = e - base;
        int srcj = 0;
        float w = 0.f;
        if (jj < cnt) {
            srcj = srcs[base + jj];
            w = __expf(lrelu(es[srcj * 4 + myh] + edh));
        }
        psum += w;
#pragma unroll
        for (int j2 = 0; j2 < 16; ++j2) {
            int src = __shfl(srcj, j2 * 4);
            float wc = __shfl(w, j2 * 4 + hc);
            unsigned p = h1b[(size_t)src * 64 + lane];
            ax = fmaf(bflo(p), wc, ax);
            ay = fmaf(bfhi(p), wc, ay);
        }
    }
#pragma unroll
    for (int mask = 4; mask <= 32; mask <<= 1) psum += __shfl_xor(psum, mask);
    float inv = 1.f / __shfl(psum, hc);
    float2 o;
    o.x = fmaxf(ax * inv, 0.f);   // fused inter-layer ReLU
    o.y = fmaxf(ay * inv, 0.f);
    ((float2*)out1)[(size_t)n * 64 + lane] = o;
}

// ---------------- layer-2 fused softmax+aggregate: half-wave per node ----------------
__global__ void k_agg2(const unsigned* __restrict__ h2b, const float* __restrict__ es,
                       const float* __restrict__ ed, const int* __restrict__ off,
                       const int* __restrict__ srcs, float* __restrict__ outv) {
    int n = blockIdx.x * (blockDim.x >> 5) + (threadIdx.x >> 5);
    int l = threadIdx.x & 31;
    int hb = threadIdx.x & 32;   // base lane of my half within the wave
    if (n >= N_NODES) return;
    float edv = ed[n];
    int s = off[n], e = off[n + 1];
    float ax = 0.f, ay = 0.f, psum = 0.f;
    for (int base = s; base < e; base += 32) {
        int cnt = e - base;
        int srcj = 0;
        float w = 0.f;
        if (l < cnt) {
            srcj = srcs[base + l];
            w = __expf(lrelu(es[srcj] + edv));
        }
        psum += w;
#pragma unroll
        for (int j = 0; j < 32; ++j) {
            int src = __shfl(srcj, hb + j);
            float wj = __shfl(w, hb + j);
            unsigned p = h2b[(size_t)src * 32 + l];
            ax = fmaf(bflo(p), wj, ax);
            ay = fmaf(bfhi(p), wj, ay);
        }
    }
#pragma unroll
    for (int mask = 1; mask <= 16; mask <<= 1) psum += __shfl_xor(psum, mask);
    float inv = 1.f / psum;
    float2 o; o.x = ax * inv; o.y = ay * inv;
    ((float2*)outv)[(size_t)n * 32 + l] = o;
}

extern "C" void kernel_launch(void* const* d_in, const int* in_sizes, int n_in,
                              void* d_out, int out_size, void* d_ws, size_t ws_size,
                              hipStream_t stream) {
    const float* x     = (const float*)d_in[0];
    const int*   ei    = (const int*)d_in[1];
    const float* W1    = (const float*)d_in[2];
    const float* attn1 = (const float*)d_in[3];
    const float* W2    = (const float*)d_in[4];
    const float* attn2 = (const float*)d_in[5];
    const float* headW = (const float*)d_in[6];
    const float* headb = (const float*)d_in[7];
    float* out = (float*)d_out;

    char* ws = (char*)d_ws;
    size_t o = 0;
    auto alloc = [&](size_t bytes) -> void* {
        o = (o + 255) & ~(size_t)255;
        void* p = ws + o;
        o += bytes;
        return p;
    };
    unsigned* h1b    = (unsigned*)alloc((size_t)N_NODES * 128 * 2);  // bf16 packed
    float*    out1   = (float*)alloc((size_t)N_NODES * 128 * 4);
    unsigned* h2b    = (unsigned*)alloc((size_t)N_NODES * 64 * 2);   // bf16 packed
    float*    h2agg  = (float*)alloc((size_t)N_NODES * 64 * 4);
    float*    e1s    = (float*)alloc((size_t)N_NODES * 4 * 4);
    float*    e1d    = (float*)alloc((size_t)N_NODES * 4 * 4);
    float*    e2s    = (float*)alloc((size_t)N_NODES * 4);
    float*    e2d    = (float*)alloc((size_t)N_NODES * 4);
    int*      deg    = (int*)alloc((size_t)N_NODES * 4);
    int*      off    = (int*)alloc((size_t)(N_NODES + 1) * 4);
    int*      cur    = (int*)alloc((size_t)N_NODES * 4);
    int*      srcs   = (int*)alloc((size_t)E_TOT * 4);
    int*      blksum = (int*)alloc((size_t)NBLK * 4);
    int*      blkoff = (int*)alloc((size_t)NBLK * 4);

    // CSR build
    hipMemsetAsync(deg, 0, (size_t)N_NODES * 4, stream);
    k_deg<<<(E_TOT + 255) / 256, 256, 0, stream>>>(ei, deg);
    k_scan1<<<NBLK, 1024, 0, stream>>>(deg, off, blksum);
    k_scan2<<<1, 64, 0, stream>>>(blksum, blkoff, off);
    k_scan3<<<(N_NODES + 255) / 256, 256, 0, stream>>>(off, blkoff, cur);
    k_scatter<<<(E_TOT + 255) / 256, 256, 0, stream>>>(ei, cur, srcs);

    // layer 1 (edot fused into GEMM epilogue; h1 stored bf16)
    k_gemm<128, 128, 1><<<N_NODES / 16, 128, 0, stream>>>(x, W1, attn1, h1b, e1s, e1d);
    k_agg1<<<N_NODES / 4, 256, 0, stream>>>(h1b, e1s, e1d, off, srcs, out1);

    // layer 2
    k_gemm<128, 64, 2><<<N_NODES / 16, 64, 0, stream>>>(out1, W2, attn2, h2b, e2s, e2d);
    k_agg2<<<N_NODES / 8, 256, 0, stream>>>(h2b, e2s, e2d, off, srcs, h2agg);

    // head
    k_gemm<64, 64, 3><<<N_NODES / 16, 64, 0, stream>>>(h2agg, headW, headb, out, nullptr, nullptr);
}